// Round 5
// baseline (153.177 us; speedup 1.0000x reference)
//
#include <hip/hip_runtime.h>
#include <stdint.h>

#define BM 128
#define BN 128
#define KD 256     // K dimension; kernel assumes 256, B=8192

typedef __attribute__((ext_vector_type(4))) float f32x4;
typedef __attribute__((ext_vector_type(4))) int   i32x4;
typedef __attribute__((ext_vector_type(8))) int   i32x8;

// Kernel 1: per-row normalize, convert to fp8 e4m3 (OCP HW cvt); fp32 diag.
// Lane l handles elements [4l, 4l+4). Also zeroes d_out.
__global__ __launch_bounds__(256) void norm_kernel(
    const float* __restrict__ a, const float* __restrict__ b,
    unsigned int* __restrict__ an, unsigned int* __restrict__ bn,
    float* __restrict__ diag, float* __restrict__ out, int D) {
  if (blockIdx.x == 0 && threadIdx.x == 0) out[0] = 0.f;
  const int row = blockIdx.x * 4 + (threadIdx.x >> 6);
  const int l = threadIdx.x & 63;
  const float4 av = ((const float4*)(a + (size_t)row * D))[l];
  const float4 bv = ((const float4*)(b + (size_t)row * D))[l];
  float ssa = av.x*av.x + av.y*av.y + av.z*av.z + av.w*av.w;
  float ssb = bv.x*bv.x + bv.y*bv.y + bv.z*bv.z + bv.w*bv.w;
  float dot = av.x*bv.x + av.y*bv.y + av.z*bv.z + av.w*bv.w;
  for (int off = 1; off < 64; off <<= 1) {
    ssa += __shfl_xor(ssa, off, 64);
    ssb += __shfl_xor(ssb, off, 64);
    dot += __shfl_xor(dot, off, 64);
  }
  const float inva = 1.0f / sqrtf(ssa);
  const float invb = 1.0f / sqrtf(ssb);
  if (l == 0) diag[row] = dot * inva * invb;
  int pa = 0, pb = 0;
  pa = __builtin_amdgcn_cvt_pk_fp8_f32(av.x * inva, av.y * inva, pa, 0);
  pa = __builtin_amdgcn_cvt_pk_fp8_f32(av.z * inva, av.w * inva, pa, 1);
  pb = __builtin_amdgcn_cvt_pk_fp8_f32(bv.x * invb, bv.y * invb, pb, 0);
  pb = __builtin_amdgcn_cvt_pk_fp8_f32(bv.z * invb, bv.w * invb, pb, 1);
  an[(size_t)row * (D / 4) + l] = (unsigned int)pa;
  bn[(size_t)row * (D / 4) + l] = (unsigned int)pb;
}

// Kernel 2: DUAL-GEMM short-kernel fp8 tile + lane-local maxes.
// Grid = 4096 single-tile blocks (ti,tj), 512 threads (8 waves, 2x4 grid:
// wave (wm,wn) owns 64x32 of the 128x128 tile). 33KB LDS -> 2 blocks/CU,
// 4 waves/SIMD; block turnover (16 turns/CU) provides latency hiding --
// the mechanism that beat every persistent variant (r0 36.5 vs r3/r4
// 66/57 us).
// Key change vs all prior rounds: NO cross-lane row reduction. Each wave
// computes BOTH C (A-frag x B-frag) and C' = transposed tile (B-frag x
// A-frag -- operands already in registers, zero extra memory traffic).
// MFMA C/D layout has the column index lane-local (col=lane&15), so:
//   col-max of C  (over regs mt,r)  = column partials of sm
//   col-max of C' (over regs nt,r)  = ROW partials of sm
// Both fold in-register + 2 shfl_xor (hi-fold). The 64-bpermute chains,
// label-LDS, and red-overlay of earlier rounds are all gone. 2 barriers
// per block (post-stage, pre-colwrite).
// A staged via swizzled global_load_lds (proven r0 scheme: stored chunk of
// src chunk c, row r = ((c&7)^(r&7))|(c&8); reads at p0/p1 undo it).
// B-frags loaded direct from L2 (64B runs, 16 rows/instr).
__global__ __launch_bounds__(512, 4) void gemm_max_kernel(
    const unsigned char* __restrict__ an, const unsigned char* __restrict__ bn,
    const int* __restrict__ labels,
    float* __restrict__ row_part, float* __restrict__ col_part, int B) {
  __shared__ __align__(16) unsigned char sA[BM * KD];   // 32 KB
  __shared__ float lds_col[2][BN];                      // 1 KB

  const int tid  = threadIdx.x;
  const int lane = tid & 63;
  const int w    = tid >> 6;            // 0..7
  const int wm   = w >> 2, wn = w & 3;  // 2 x 4 wave grid (64 rows x 32 cols)
  const int tj   = blockIdx.x & 63;     // fast-varying: A-panel L2 reuse
  const int ti   = blockIdx.x >> 6;

  // staging decomposition
  const int sr = lane >> 4;             // row within 4-row group
  const int sc = lane & 15;             // dest 16B-chunk position
  // fragment decomposition
  const int fr = lane & 15;             // m/n index
  const int hi = lane >> 4;             // k-quad
  const int p0 = ((2 * hi)     ^ (fr & 7)) * 16;
  const int p1 = ((2 * hi + 1) ^ (fr & 7)) * 16;

  // ---- Stage A-panel (32 KB, 4 passes x 8 waves x 4 rows) ----
  #pragma unroll
  for (int pass = 0; pass < 4; ++pass) {
    const int r0  = pass * 32 + w * 4;
    const int row = r0 + sr;
    const int g = ((sc & 7) ^ (row & 7)) | (sc & 8);
    const unsigned char* ga = an + (size_t)(ti * BM + row) * KD + g * 16;
    __builtin_amdgcn_global_load_lds(
        (const __attribute__((address_space(1))) void*)ga,
        (__attribute__((address_space(3))) void*)(sA + r0 * KD + lane * 16),
        16, 0, 0);
  }

  // ---- B-frags direct to registers (each wave: its own 32 columns) ----
  i32x8 bfr[2][2];
  #pragma unroll
  for (int it = 0; it < 2; ++it)
    #pragma unroll
    for (int nt = 0; nt < 2; ++nt) {
      const unsigned char* gb =
          bn + (size_t)(tj * BN + wn * 32 + nt * 16 + fr) * KD + it * 128 + hi * 32;
      bfr[it][nt] = __builtin_shufflevector(*(const i32x4*)gb,
                                            *(const i32x4*)(gb + 16),
                                            0, 1, 2, 3, 4, 5, 6, 7);
    }
  __syncthreads();   // A-panel landed

  const int SC = 0x7F7F7F7F;            // E8M0 = 1.0 in all byte slots
  f32x4 acc[4][2], at[4][2];            // C and C' (transposed) tiles
  #pragma unroll
  for (int mt = 0; mt < 4; ++mt)
    #pragma unroll
    for (int nt = 0; nt < 2; ++nt) {
      acc[mt][nt] = (f32x4){0.f, 0.f, 0.f, 0.f};
      at[mt][nt]  = (f32x4){0.f, 0.f, 0.f, 0.f};
    }

  #pragma unroll
  for (int it = 0; it < 2; ++it)
    #pragma unroll
    for (int mt = 0; mt < 4; ++mt) {
      const unsigned char* ra = sA + (wm * 64 + mt * 16 + fr) * KD + it * 128;
      const i32x8 af = __builtin_shufflevector(*(const i32x4*)(ra + p0),
                                               *(const i32x4*)(ra + p1),
                                               0, 1, 2, 3, 4, 5, 6, 7);
      acc[mt][0] = __builtin_amdgcn_mfma_scale_f32_16x16x128_f8f6f4(
          af, bfr[it][0], acc[mt][0], 0, 0, 0, SC, 0, SC);
      acc[mt][1] = __builtin_amdgcn_mfma_scale_f32_16x16x128_f8f6f4(
          af, bfr[it][1], acc[mt][1], 0, 0, 0, SC, 0, SC);
      at[mt][0] = __builtin_amdgcn_mfma_scale_f32_16x16x128_f8f6f4(
          bfr[it][0], af, at[mt][0], 0, 0, 0, SC, 0, SC);
      at[mt][1] = __builtin_amdgcn_mfma_scale_f32_16x16x128_f8f6f4(
          bfr[it][1], af, at[mt][1], 0, 0, 0, SC, 0, SC);
    }

  // ---- Labels (all from hot L2; loaded only now to cap VGPR pressure) ----
  // C  layout: acc[mt][nt][r] = sm[i,j], i = wm*64+mt*16+hi*4+r, j = tj*BN+wn*32+nt*16+fr
  // C' layout: at[mt][nt][r]  = sm[i,j], i = wm*64+mt*16+fr,     j = tj*BN+wn*32+nt*16+hi*4+r
  const int labc0 = labels[tj * BN + wn * 32 + fr];
  const int labc1 = labels[tj * BN + wn * 32 + 16 + fr];
  i32x4 lv[4], labj[2];
  int la[4];
  #pragma unroll
  for (int mt = 0; mt < 4; ++mt) {
    lv[mt] = *(const i32x4*)&labels[ti * BM + wm * 64 + mt * 16 + hi * 4];
    la[mt] = labels[ti * BM + wm * 64 + mt * 16 + fr];
  }
  #pragma unroll
  for (int nt = 0; nt < 2; ++nt)
    labj[nt] = *(const i32x4*)&labels[tj * BN + wn * 32 + nt * 16 + hi * 4];

  // ---- Column partials from C (lane-local over mt,r; then hi-fold) ----
  float cp0 = -1e9f, cp1 = -1e9f;
  #pragma unroll
  for (int mt = 0; mt < 4; ++mt)
    #pragma unroll
    for (int r = 0; r < 4; ++r) {
      const int l0 = lv[mt][r];
      cp0 = fmaxf(cp0, (l0 != labc0) ? acc[mt][0][r] : -1e9f);
      cp1 = fmaxf(cp1, (l0 != labc1) ? acc[mt][1][r] : -1e9f);
    }
  cp0 = fmaxf(cp0, __shfl_xor(cp0, 16, 64));
  cp0 = fmaxf(cp0, __shfl_xor(cp0, 32, 64));
  cp1 = fmaxf(cp1, __shfl_xor(cp1, 16, 64));
  cp1 = fmaxf(cp1, __shfl_xor(cp1, 32, 64));
  if (hi == 0) {
    lds_col[wm][wn * 32 + fr] = cp0;
    lds_col[wm][wn * 32 + 16 + fr] = cp1;
  }

  // ---- Row partials from C' (lane-local over nt,r; then hi-fold) ----
  #pragma unroll
  for (int mt = 0; mt < 4; ++mt) {
    const int lam = la[mt];
    float rm = -1e9f;
    #pragma unroll
    for (int nt = 0; nt < 2; ++nt)
      #pragma unroll
      for (int r = 0; r < 4; ++r)
        rm = fmaxf(rm, (lam != labj[nt][r]) ? at[mt][nt][r] : -1e9f);
    rm = fmaxf(rm, __shfl_xor(rm, 16, 64));
    rm = fmaxf(rm, __shfl_xor(rm, 32, 64));
    if (hi == 0)
      row_part[(size_t)(tj * 4 + wn) * B + ti * BM + wm * 64 + mt * 16 + fr] = rm;
  }

  // ---- Combine the two wm halves of the column partials ----
  __syncthreads();
  if (tid < BN)
    col_part[(size_t)ti * B + tj * BN + tid] =
        fmaxf(lds_col[0][tid], lds_col[1][tid]);
}

// Kernel 3: reduce per-slot maxes -> M; threshold; per-row loss; atomicAdd.
// Row dir: Tr=256 slots (tj x wn); col dir: Tc=64 (ti). Wave-per-quarter
// split for load parallelism (grid = 2B/64 = 256 blocks).
__global__ __launch_bounds__(256) void finalize_kernel(
    const float* __restrict__ row_part, const float* __restrict__ col_part,
    const float* __restrict__ diag, int B, int Tr, int Tc,
    float* __restrict__ out) {
  const int ln = threadIdx.x & 63;
  const int q  = threadIdx.x >> 6;           // wave = quarter of the T range
  const int item = blockIdx.x * 64 + ln;     // 0..2B-1
  const bool isrow = item < B;
  const int i = isrow ? item : item - B;
  const float* part = isrow ? row_part : col_part;
  const int T = isrow ? Tr : Tc;
  const int tpq = (T + 3) >> 2;
  const int t1 = min(T, (q + 1) * tpq);
  float m = -1e9f;
  for (int t = q * tpq; t < t1; ++t) m = fmaxf(m, part[(size_t)t * B + i]);
  __shared__ float smq[4][64];
  smq[q][ln] = m;
  __syncthreads();
  if (q == 0) {
    m = fmaxf(fmaxf(smq[0][ln], smq[1][ln]), fmaxf(smq[2][ln], smq[3][ln]));
    const float d = diag[i];
    float loss = 0.f;
    if ((d < 1.0f - 1e-5f) && (m + 0.2f > d)) {
      loss = fmaxf(0.2f * d * d - 0.7f * d + 0.5f, 0.f) +
             fmaxf(0.9f * m * m - 0.4f * m + 0.03f, 0.f);
    }
    for (int off = 1; off < 64; off <<= 1) loss += __shfl_xor(loss, off, 64);
    if (ln == 0) atomicAdd(out, loss / (float)B);
  }
}

extern "C" void kernel_launch(void* const* d_in, const int* in_sizes, int n_in,
                              void* d_out, int out_size, void* d_ws, size_t ws_size,
                              hipStream_t stream) {
  const float* a      = (const float*)d_in[0];
  const float* b      = (const float*)d_in[1];
  const int*   labels = (const int*)d_in[2];
  const int B = in_sizes[2];
  const int D = in_sizes[0] / B;       // 256
  const int Tr = (B / BN) * 4;         // 256 row partial slots (tj x wn)
  const int Tc = B / BM;               // 64 col partial slots (ti)

  char* ws = (char*)d_ws;
  unsigned char* an = (unsigned char*)ws;                    // B*D fp8
  unsigned char* bn = (unsigned char*)(ws + (size_t)B * D);  // B*D fp8
  float* diag     = (float*)(ws + (size_t)2 * B * D);        // B*4
  float* row_part = diag + B;                                // Tr*B*4
  float* col_part = row_part + (size_t)Tr * B;               // Tc*B*4

  norm_kernel<<<B / 4, 256, 0, stream>>>(a, b, (unsigned int*)an,
                                         (unsigned int*)bn, diag,
                                         (float*)d_out, D);

  gemm_max_kernel<<<(B / BM) * (B / BN), 512, 0, stream>>>(
      an, bn, labels, row_part, col_part, B);

  finalize_kernel<<<(2 * B) / 64, 256, 0, stream>>>(
      row_part, col_part, diag, B, Tr, Tc, (float*)d_out);
}